// Round 2
// baseline (431.698 us; speedup 1.0000x reference)
//
#include <hip/hip_runtime.h>
#include <hip/hip_bf16.h>
#include <cstdint>
#include <cstddef>

typedef __attribute__((ext_vector_type(8))) short short8;
typedef __attribute__((ext_vector_type(16))) float float16;

// Problem constants: B=8, C=512, H=W=14, HS=1024, K=144 centers (12x12), O=9 offsets.

static __device__ __forceinline__ unsigned short f2bf(float f) {
  union { float f; unsigned int u; } v; v.f = f;
  unsigned int r = v.u + 0x7fffu + ((v.u >> 16) & 1u);
  return (unsigned short)(r >> 16);
}

// -------- Kernel 1: projection GEMM --------
// out[h][p] = sum_c w[h][c] * x[b][c][p] + bias[h], stacked (w1;w2) as M=2048.
// Tiles: 128 h x 64 p per block, K=512 in chunks of 64. P[mat][b][h][p] bf16.
__global__ __launch_bounds__(256, 2)
void proj_kernel(const float* __restrict__ x,
                 const float* __restrict__ w1, const float* __restrict__ b1,
                 const float* __restrict__ w2, const float* __restrict__ b2,
                 unsigned short* __restrict__ P)
{
  const int nt = blockIdx.x;         // 0..3   p-tile (64)
  const int mt = blockIdx.y;         // 0..15  h-tile (128)
  const int b  = blockIdx.z;         // 0..7
  const int mat = (mt >= 8) ? 1 : 0;
  const float* __restrict__ w    = mat ? w2 : w1;
  const float* __restrict__ bias = mat ? b2 : b1;
  const int h0 = (mt - mat * 8) * 128;
  const int p0 = nt * 64;

  __shared__ unsigned short As[128 * 72];
  __shared__ unsigned short Bs[64 * 72];

  const int tid  = threadIdx.x;
  const int lane = tid & 63, wave = tid >> 6;
  const int ln31 = lane & 31, lh = lane >> 5;

  float16 acc0, acc1;
  #pragma unroll
  for (int r = 0; r < 16; ++r) { acc0[r] = 0.f; acc1[r] = 0.f; }

  for (int kc = 0; kc < 512; kc += 64) {
    #pragma unroll
    for (int i = 0; i < 8; ++i) {
      int idx = tid + i * 256;
      int row = idx >> 4;
      int c4  = (idx & 15) << 2;
      const float4 v = *(const float4*)&w[(size_t)(h0 + row) * 512 + kc + c4];
      unsigned short* dst = &As[row * 72 + c4];
      dst[0] = f2bf(v.x); dst[1] = f2bf(v.y); dst[2] = f2bf(v.z); dst[3] = f2bf(v.w);
    }
    #pragma unroll
    for (int i = 0; i < 16; ++i) {
      int idx = tid + i * 256;
      int c  = idx >> 6;
      int pl = idx & 63;
      int p  = p0 + pl;
      float val = 0.f;
      if (p < 196) val = x[((size_t)b * 512 + kc + c) * 196 + p];
      Bs[pl * 72 + c] = f2bf(val);
    }
    __syncthreads();
    #pragma unroll
    for (int ks = 0; ks < 4; ++ks) {
      short8 a   = *(const short8*)&As[(wave * 32 + ln31) * 72 + ks * 16 + lh * 8];
      short8 bb0 = *(const short8*)&Bs[(ln31) * 72 + ks * 16 + lh * 8];
      short8 bb1 = *(const short8*)&Bs[(32 + ln31) * 72 + ks * 16 + lh * 8];
      acc0 = __builtin_amdgcn_mfma_f32_32x32x16_bf16(a, bb0, acc0, 0, 0, 0);
      acc1 = __builtin_amdgcn_mfma_f32_32x32x16_bf16(a, bb1, acc1, 0, 0, 0);
    }
    __syncthreads();
  }

  #pragma unroll
  for (int r = 0; r < 16; ++r) {
    int rowl = (r & 3) + ((r >> 2) << 3) + (lh << 2);
    int h = h0 + wave * 32 + rowl;
    float bi = bias[h];
    size_t base = ((size_t)(mat * 8 + b) * 1024 + h) * 196;
    int p_a = p0 + ln31;
    if (p_a < 196) P[base + p_a] = f2bf(acc0[r] + bi);
    int p_b = p_a + 32;
    if (p_b < 196) P[base + p_b] = f2bf(acc1[r] + bi);
  }
}

// -------- Kernel 2: gather into MFMA-swizzled layouts (LDS-staged) --------
// Block = (jt 0..31, task 0..1, b 0..7). Stage 32 rows of P (j0..j0+31) into
// LDS via coalesced u32 loads, precompute pos0[144] center-position table,
// then emit swizzled uint4 chunks:
//   cpz chunk ((b*9+s)*1024 + i)*2 + h        (task 0, from P1, offset 0)
//   spz chunk (((o*8+b)*9+s)*1024 + j)*2 + h  (task 1, from P2, all 9 offsets)
__global__ __launch_bounds__(256)
void gather_kernel(const unsigned short* __restrict__ P,
                   unsigned short* __restrict__ cpz,
                   unsigned short* __restrict__ spz)
{
  const int jt   = blockIdx.x;   // 0..31
  const int task = blockIdx.y;   // 0 = cpz, 1 = spz
  const int b    = blockIdx.z;   // 0..7
  const int tid  = threadIdx.x;
  const int j0   = jt * 32;

  __shared__ unsigned short rows[32 * 200];
  __shared__ unsigned short pos0[144];
  __shared__ unsigned short pad_[8];   // keep 16B headroom after pos0

  if (tid < 144) {
    int ky = tid / 12, kx = tid % 12;
    pos0[tid] = (unsigned short)((ky + 1) * 14 + (kx + 1));
  }
  (void)pad_;

  const unsigned short* src =
      P + ((size_t)(task * 8 + b) * 1024 + j0) * 196;
  const unsigned int* src32 = (const unsigned int*)src;
  #pragma unroll
  for (int i = 0; i < 13; ++i) {
    int idx = tid + i * 256;            // 0..3135  (32 rows x 98 u32)
    if (idx < 3136) {
      int row = idx / 98;
      int c   = idx - row * 98;
      ((unsigned int*)&rows[row * 200])[c] = src32[idx];
    }
  }
  __syncthreads();

  unsigned short tmp[8];
  if (task == 0) {
    // 576 chunks: t = (s:4)(row:5)(h:1)
    for (int t = tid; t < 576; t += 256) {
      int h = t & 1, row = (t >> 1) & 31, s = t >> 6;
      int kb = s * 16 + h * 8;
      const unsigned short* rp = &rows[row * 200];
      short8 ps = *(const short8*)&pos0[kb];
      #pragma unroll
      for (int e = 0; e < 8; ++e) tmp[e] = rp[(unsigned short)ps[e]];
      size_t chunk = ((size_t)(b * 9 + s) * 1024 + j0 + row) * 2 + h;
      *(uint4*)(cpz + chunk * 8) = *(const uint4*)tmp;
    }
  } else {
    // 5184 chunks: t = (q=o*9+s:7)(row:5)(h:1)
    for (int t = tid; t < 5184; t += 256) {
      int h = t & 1, row = (t >> 1) & 31, q = t >> 6;
      int o = q / 9, s = q - o * 9;
      int doff = (o / 3 - 1) * 14 + (o % 3 - 1);
      int kb = s * 16 + h * 8;
      const unsigned short* rp = &rows[row * 200];
      short8 ps = *(const short8*)&pos0[kb];
      #pragma unroll
      for (int e = 0; e < 8; ++e) tmp[e] = rp[(unsigned short)ps[e] + doff];
      size_t chunk = (((size_t)(o * 8 + b) * 9 + s) * 1024 + j0 + row) * 2 + h;
      *(uint4*)(spz + chunk * 8) = *(const uint4*)tmp;
    }
  }
}

// -------- Kernel 3: cofe GEMM + fused row-normalization --------
// Block = (iblk 0..15, o 0..8, b 0..7): 64 rows x 1024 cols. 8 waves:
// wave w -> i-strip (w>>2)*32, j-quarter (w&3)*256 (8 tiles of 32x32).
// K=144 = 9 MFMA(32x32x16) steps; operand loads are coalesced 16B/lane.
// Output stores are nontemporal (write-once, keep L2/L3 for spz).
__global__ __launch_bounds__(512, 2)
void cofe_kernel(const unsigned short* __restrict__ cpz,
                 const unsigned short* __restrict__ spz,
                 float* __restrict__ out)
{
  const int iblk = blockIdx.x;   // 0..15
  const int o    = blockIdx.y;   // 0..8
  const int b    = blockIdx.z;   // 0..7
  const int tid  = threadIdx.x;
  const int lane = tid & 63, wave = tid >> 6;
  const int ln31 = lane & 31, lh = lane >> 5;
  const int istrip = (iblk << 6) + ((wave >> 2) << 5);   // global i base of strip
  const int jw = (wave & 3) << 8;

  float16 acc[8];
  #pragma unroll
  for (int t = 0; t < 8; ++t) {
    #pragma unroll
    for (int r = 0; r < 16; ++r) acc[t][r] = 0.f;
  }

  const uint4* A  = (const uint4*)cpz;
  const uint4* Bp = (const uint4*)spz;
  const size_t abase = ((size_t)b * 9 * 1024 + istrip + ln31) * 2 + lh;
  const size_t bbase = ((size_t)(o * 8 + b) * 9 * 1024 + jw + ln31) * 2 + lh;

  #pragma unroll
  for (int s = 0; s < 9; ++s) {
    short8 a = *(const short8*)(A + abase + (size_t)s * 2048);
    #pragma unroll
    for (int t = 0; t < 8; ++t) {
      short8 bb = *(const short8*)(Bp + bbase + (size_t)s * 2048 + t * 64);
      acc[t] = __builtin_amdgcn_mfma_f32_32x32x16_bf16(a, bb, acc[t], 0, 0, 0);
    }
  }

  // per-row sum of squares over this wave's 256 cols
  float ssq[16];
  #pragma unroll
  for (int r = 0; r < 16; ++r) {
    float s2 = 0.f;
    #pragma unroll
    for (int t = 0; t < 8; ++t) s2 += acc[t][r] * acc[t][r];
    ssq[r] = s2;
  }
  #pragma unroll
  for (int m = 1; m <= 16; m <<= 1) {
    #pragma unroll
    for (int r = 0; r < 16; ++r) ssq[r] += __shfl_xor(ssq[r], m, 64);
  }

  __shared__ float s_ssq[64];
  if (tid < 64) s_ssq[tid] = 0.f;
  __syncthreads();
  if (ln31 == 0) {            // lanes 0 and 32 of each wave hold half-sums
    int rbase = (wave >> 2) << 5;
    #pragma unroll
    for (int r = 0; r < 16; ++r) {
      int rowl = (r & 3) + ((r >> 2) << 3) + (lh << 2);
      atomicAdd(&s_ssq[rbase + rowl], ssq[r]);
    }
  }
  __syncthreads();

  const size_t outbase = ((size_t)(b * 9 + o) << 20) + ((size_t)istrip << 10) + jw + ln31;
  const int rbase = (wave >> 2) << 5;
  #pragma unroll
  for (int r = 0; r < 16; ++r) {
    int rowl = (r & 3) + ((r >> 2) << 3) + (lh << 2);
    float nrm = sqrtf(s_ssq[rbase + rowl]);
    float sc = 1.f / fmaxf(nrm, 1e-12f);
    size_t rb = outbase + ((size_t)rowl << 10);
    #pragma unroll
    for (int t = 0; t < 8; ++t)
      __builtin_nontemporal_store(acc[t][r] * sc, &out[rb + (t << 5)]);
  }
}

extern "C" void kernel_launch(void* const* d_in, const int* in_sizes, int n_in,
                              void* d_out, int out_size, void* d_ws, size_t ws_size,
                              hipStream_t stream)
{
  const float* x  = (const float*)d_in[0];
  const float* w1 = (const float*)d_in[1];
  const float* b1 = (const float*)d_in[2];
  const float* w2 = (const float*)d_in[3];
  const float* b2 = (const float*)d_in[4];
  float* out = (float*)d_out;

  // workspace layout (bf16 as ushort):
  // P   : [2][8][1024][196]          = 3,211,264 elems
  // cpz : [8][9][1024][2][8]         = 1,179,648 elems
  // spz : [9][8][9][1024][2][8]      = 10,616,832 elems   (~30 MB total)
  unsigned short* P   = (unsigned short*)d_ws;
  unsigned short* cpz = P + (size_t)2 * 8 * 1024 * 196;
  unsigned short* spz = cpz + (size_t)8 * 9 * 1024 * 16;

  proj_kernel<<<dim3(4, 16, 8), 256, 0, stream>>>(x, w1, b1, w2, b2, P);
  gather_kernel<<<dim3(32, 2, 8), 256, 0, stream>>>(P, cpz, spz);
  cofe_kernel<<<dim3(16, 9, 8), 512, 0, stream>>>(cpz, spz, out);
}